// Round 3
// baseline (419.537 us; speedup 1.0000x reference)
//
#include <hip/hip_runtime.h>
#include <hip/hip_bf16.h>
#include <stdint.h>

// Problem dims (fixed)
#define BB 4
#define TT 1024
#define SS 1024
#define EE 768      // embed dim = H*D
#define HH 12
#define DDIM 64
#define MM 3072
#define NROWS 4096  // B*T
#define ATT_SCALE 0.125f

typedef unsigned short u16;
using short8 = __attribute__((ext_vector_type(8))) short;
using f32x4  = __attribute__((ext_vector_type(4))) float;

__device__ inline f32x4 mfma16(short8 a, short8 b, f32x4 c) {
  return __builtin_amdgcn_mfma_f32_16x16x32_bf16(a, b, c, 0, 0, 0);
}

__device__ inline float b2f(u16 u) {
  union { uint32_t i; float f; } z; z.i = ((uint32_t)u) << 16; return z.f;
}
__device__ inline u16 f2b(float f) {
  __hip_bfloat16 h = __float2bfloat16(f);
  return *reinterpret_cast<u16*>(&h);
}
__device__ inline float loadf(const float* p) { return *p; }
__device__ inline float loadf(const u16* p) { return b2f(*p); }

__device__ inline float gelu_f(float x) {
  const float k0 = 0.7978845608028654f; // sqrt(2/pi)
  const float k1 = 0.044715f;
  float t = tanhf(k0 * (x + k1 * x * x * x));
  return 0.5f * x * (1.0f + t);
}

// ------- transpose+convert: in fp32 [batch][R][C] -> out bf16 [batch][C][R] -
__global__ void transpose_k(const float* __restrict__ in, u16* __restrict__ out,
                            int R, int C) {
  __shared__ u16 tile[32][34];
  int bz = blockIdx.z;
  const float* ip = in + (size_t)bz * R * C;
  u16* op = out + (size_t)bz * R * C;
  int r0 = blockIdx.y * 32, c0 = blockIdx.x * 32;
  int tx = threadIdx.x, ty = threadIdx.y; // 32 x 8
#pragma unroll
  for (int j = 0; j < 32; j += 8)
    tile[ty + j][tx] = f2b(ip[(size_t)(r0 + ty + j) * C + (c0 + tx)]);
  __syncthreads();
#pragma unroll
  for (int j = 0; j < 32; j += 8)
    op[(size_t)(c0 + ty + j) * R + (r0 + tx)] = tile[tx][ty + j];
}

// ---------------- LayerNorm over last dim 768 -> bf16 out -------------------
template <typename T>
__global__ __launch_bounds__(256) void layernorm_k(const T* __restrict__ x,
    const float* __restrict__ g, const float* __restrict__ b,
    u16* __restrict__ y) {
  int row = blockIdx.x, t = threadIdx.x;
  const T* xr = x + (size_t)row * EE;
  float v0 = loadf(xr + t), v1 = loadf(xr + t + 256), v2 = loadf(xr + t + 512);
  float s = v0 + v1 + v2;
#pragma unroll
  for (int m = 32; m >= 1; m >>= 1) s += __shfl_xor(s, m);
  __shared__ float red[8];
  int wv = t >> 6, ln = t & 63;
  if (ln == 0) red[wv] = s;
  __syncthreads();
  float mean = (red[0] + red[1] + red[2] + red[3]) * (1.0f / EE);
  float d0 = v0 - mean, d1 = v1 - mean, d2 = v2 - mean;
  float s2 = d0 * d0 + d1 * d1 + d2 * d2;
#pragma unroll
  for (int m = 32; m >= 1; m >>= 1) s2 += __shfl_xor(s2, m);
  if (ln == 0) red[4 + wv] = s2;
  __syncthreads();
  float var = (red[4] + red[5] + red[6] + red[7]) * (1.0f / EE);
  float rstd = rsqrtf(var + 1e-5f);
  u16* yr = y + (size_t)row * EE;
  yr[t]       = f2b(d0 * rstd * g[t]       + b[t]);
  yr[t + 256] = f2b(d1 * rstd * g[t + 256] + b[t + 256]);
  yr[t + 512] = f2b(d2 * rstd * g[t + 512] + b[t + 512]);
}

// ---------------- GEMM: C[M,N] = A[M,K] @ Bt[N,K]^T + bias (+res)(gelu) -----
// A: bf16 (u16) or fp32, row-major lda=K. Bt bf16 row-major ldb=K.
// RESMODE: 0 none, 1 fp32 residual, 2 bf16 residual.
template <typename AT, int RESMODE, bool GELU, typename OutT>
__global__ __launch_bounds__(256) void gemm_k(
    const AT* __restrict__ A, const u16* __restrict__ Bt,
    const float* __restrict__ bias, const void* __restrict__ res,
    OutT* __restrict__ C, int M, int N, int K) {
  __shared__ u16 As[64][40]; // +8 pad: conflict-free b128 reads
  __shared__ u16 Bs[64][40];
  int bm = blockIdx.y * 64, bn = blockIdx.x * 64;
  int tid = threadIdx.x;
  int wave = tid >> 6, lane = tid & 63;
  int wr = wave >> 1, wc = wave & 1;     // wave -> 32x32 quadrant
  int g = lane >> 4, li = lane & 15;
  f32x4 acc[2][2] = {};
  int lr = tid >> 2, lc = (tid & 3) * 8; // staging coords: 64 rows x 32 cols
  const AT* Ap = A + (size_t)(bm + lr) * K + lc;
  const u16* Bp = Bt + (size_t)(bn + lr) * K + lc;
  for (int k0 = 0; k0 < K; k0 += 32) {
    if constexpr (sizeof(AT) == 2) {
      *(int4*)(&As[lr][lc]) = *(const int4*)(Ap + k0);
    } else {
      float4 fa = *(const float4*)(Ap + k0);
      float4 fb = *(const float4*)(Ap + k0 + 4);
      u16 tmp[8] = {f2b(fa.x), f2b(fa.y), f2b(fa.z), f2b(fa.w),
                    f2b(fb.x), f2b(fb.y), f2b(fb.z), f2b(fb.w)};
      *(int4*)(&As[lr][lc]) = *(const int4*)(tmp);
    }
    *(int4*)(&Bs[lr][lc]) = *(const int4*)(Bp + k0);
    __syncthreads();
    short8 a0 = *(const short8*)(&As[wr * 32 + li][g * 8]);
    short8 a1 = *(const short8*)(&As[wr * 32 + 16 + li][g * 8]);
    short8 b0 = *(const short8*)(&Bs[wc * 32 + li][g * 8]);
    short8 b1 = *(const short8*)(&Bs[wc * 32 + 16 + li][g * 8]);
    acc[0][0] = mfma16(a0, b0, acc[0][0]);
    acc[0][1] = mfma16(a0, b1, acc[0][1]);
    acc[1][0] = mfma16(a1, b0, acc[1][0]);
    acc[1][1] = mfma16(a1, b1, acc[1][1]);
    __syncthreads();
  }
#pragma unroll
  for (int mt = 0; mt < 2; mt++)
#pragma unroll
    for (int nt = 0; nt < 2; nt++) {
      int n = bn + wc * 32 + nt * 16 + li;
      float bv = bias[n];
#pragma unroll
      for (int i = 0; i < 4; i++) {
        int m = bm + wr * 32 + mt * 16 + g * 4 + i;
        float val = acc[mt][nt][i] + bv;
        if (GELU) val = gelu_f(val);
        if (RESMODE == 1) val += ((const float*)res)[(size_t)m * N + n];
        else if (RESMODE == 2) val += b2f(((const u16*)res)[(size_t)m * N + n]);
        if constexpr (sizeof(OutT) == 2) C[(size_t)m * N + n] = f2b(val);
        else                             C[(size_t)m * N + n] = val;
      }
    }
}

// ---------------- Flash attention, bf16, layout [b*T + t][h*64 + d] ---------
// grid: (T/64, H, B); 256 threads = 4 waves, wave w owns q rows w*16..w*16+15
template <bool CAUSAL>
__global__ __launch_bounds__(256) void attn_k(
    const u16* __restrict__ Q, const u16* __restrict__ Kp,
    const u16* __restrict__ Vp, u16* __restrict__ O) {
  int b = blockIdx.z, h = blockIdx.y, q0 = blockIdx.x * 64;
  int tid = threadIdx.x, wave = tid >> 6, lane = tid & 63;
  int g = lane >> 4, li = lane & 15;
  const u16* Qb = Q + (size_t)b * TT * EE + h * DDIM;
  const u16* Kb = Kp + (size_t)b * SS * EE + h * DDIM;
  const u16* Vb = Vp + (size_t)b * SS * EE + h * DDIM;
  u16* Ob = O + (size_t)b * TT * EE + h * DDIM;

  __shared__ u16 Ks[64][72];      // [t][d]
  __shared__ u16 VsT[64][72];     // [d][t]
  __shared__ u16 Ps[4][16][72];   // per-wave P [q][t]

  int qrow = q0 + wave * 16 + li;
  short8 qf0 = *(const short8*)(Qb + (size_t)qrow * EE + g * 8);
  short8 qf1 = *(const short8*)(Qb + (size_t)qrow * EE + 32 + g * 8);

  f32x4 accO[4] = {};
  float mrow[4], lrow[4];
#pragma unroll
  for (int i = 0; i < 4; i++) { mrow[i] = -1e30f; lrow[i] = 0.f; }

  int kvEnd = CAUSAL ? (q0 + 64) : SS;
  int tl = tid >> 2, d0 = (tid & 3) * 16;
  for (int kv0 = 0; kv0 < kvEnd; kv0 += 64) {
    const u16* kp = Kb + (size_t)(kv0 + tl) * EE + d0;
    *(int4*)(&Ks[tl][d0]) = *(const int4*)(kp);
    *(int4*)(&Ks[tl][d0 + 8]) = *(const int4*)(kp + 8);
    const u16* vp = Vb + (size_t)(kv0 + tl) * EE + d0;
#pragma unroll
    for (int j = 0; j < 16; j++) VsT[d0 + j][tl] = vp[j];
    __syncthreads();

    // S = Q K^T for this wave's 16 q rows x 64 t cols
    f32x4 s[4];
#pragma unroll
    for (int kt = 0; kt < 4; kt++) {
      short8 kf0 = *(const short8*)(&Ks[kt * 16 + li][g * 8]);
      short8 kf1 = *(const short8*)(&Ks[kt * 16 + li][32 + g * 8]);
      f32x4 z = {};
      z = mfma16(qf0, kf0, z);
      z = mfma16(qf1, kf1, z);
      s[kt] = z;
    }

    float rmax[4] = {-1e30f, -1e30f, -1e30f, -1e30f};
#pragma unroll
    for (int kt = 0; kt < 4; kt++)
#pragma unroll
      for (int i = 0; i < 4; i++) {
        float sv = s[kt][i] * ATT_SCALE;
        if (CAUSAL) {
          int qi = q0 + wave * 16 + g * 4 + i;
          int ti = kv0 + kt * 16 + li;
          if (ti > qi) sv = -1e30f;
        }
        s[kt][i] = sv;
        rmax[i] = fmaxf(rmax[i], sv);
      }
#pragma unroll
    for (int msk = 1; msk < 16; msk <<= 1)
#pragma unroll
      for (int i = 0; i < 4; i++) rmax[i] = fmaxf(rmax[i], __shfl_xor(rmax[i], msk));

    float corr[4], rsum[4];
#pragma unroll
    for (int i = 0; i < 4; i++) {
      float mn = fmaxf(mrow[i], rmax[i]);
      corr[i] = __expf(mrow[i] - mn);
      mrow[i] = mn;
      rsum[i] = 0.f;
    }
#pragma unroll
    for (int kt = 0; kt < 4; kt++)
#pragma unroll
      for (int i = 0; i < 4; i++) {
        float sv = s[kt][i];
        float p = (sv < -1e29f) ? 0.f : __expf(sv - mrow[i]);
        s[kt][i] = p;
        rsum[i] += p;
      }
#pragma unroll
    for (int msk = 1; msk < 16; msk <<= 1)
#pragma unroll
      for (int i = 0; i < 4; i++) rsum[i] += __shfl_xor(rsum[i], msk);
#pragma unroll
    for (int i = 0; i < 4; i++) lrow[i] = lrow[i] * corr[i] + rsum[i];
#pragma unroll
    for (int dt = 0; dt < 4; dt++)
#pragma unroll
      for (int i = 0; i < 4; i++) accO[dt][i] *= corr[i];

    // write P (bf16) to per-wave LDS, re-read as A-fragments
#pragma unroll
    for (int kt = 0; kt < 4; kt++)
#pragma unroll
      for (int i = 0; i < 4; i++)
        Ps[wave][g * 4 + i][kt * 16 + li] = f2b(s[kt][i]);

#pragma unroll
    for (int tc = 0; tc < 2; tc++) {
      short8 pf = *(const short8*)(&Ps[wave][li][tc * 32 + g * 8]);
#pragma unroll
      for (int dt = 0; dt < 4; dt++) {
        short8 vf = *(const short8*)(&VsT[dt * 16 + li][tc * 32 + g * 8]);
        accO[dt] = mfma16(pf, vf, accO[dt]);
      }
    }
    __syncthreads();
  }

#pragma unroll
  for (int i = 0; i < 4; i++) {
    float inv = 1.0f / lrow[i];
    int q = q0 + wave * 16 + g * 4 + i;
#pragma unroll
    for (int dt = 0; dt < 4; dt++)
      Ob[(size_t)q * EE + dt * 16 + li] = f2b(accO[dt][i] * inv);
  }
}

// ---------------------------------------------------------------------------
static inline void* wsoff(void* ws, size_t& off, size_t bytes) {
  void* p = (char*)ws + off;
  off += (bytes + 255) & ~(size_t)255;
  return p;
}

extern "C" void kernel_launch(void* const* d_in, const int* in_sizes, int n_in,
                              void* d_out, int out_size, void* d_ws, size_t ws_size,
                              hipStream_t stream) {
  // All inputs are fp32 per the reference dtypes.
  const float* target = (const float*)d_in[0];
  const float* memory = (const float*)d_in[1];
  const float* sa_wq = (const float*)d_in[2];  const float* sa_bq = (const float*)d_in[3];
  const float* sa_wk = (const float*)d_in[4];  const float* sa_bk = (const float*)d_in[5];
  const float* sa_wv = (const float*)d_in[6];  const float* sa_bv = (const float*)d_in[7];
  const float* sa_wo = (const float*)d_in[8];  const float* sa_bo = (const float*)d_in[9];
  const float* ca_wq = (const float*)d_in[10]; const float* ca_bq = (const float*)d_in[11];
  const float* ca_wk = (const float*)d_in[12]; const float* ca_bk = (const float*)d_in[13];
  const float* ca_wv = (const float*)d_in[14]; const float* ca_bv = (const float*)d_in[15];
  const float* ca_wo = (const float*)d_in[16]; const float* ca_bo = (const float*)d_in[17];
  const float* ln1_g = (const float*)d_in[18]; const float* ln1_b = (const float*)d_in[19];
  const float* ln2_g = (const float*)d_in[20]; const float* ln2_b = (const float*)d_in[21];
  const float* ln3_g = (const float*)d_in[22]; const float* ln3_b = (const float*)d_in[23];
  const float* ffn_w1 = (const float*)d_in[24]; const float* ffn_b1 = (const float*)d_in[25];
  const float* ffn_w2 = (const float*)d_in[26]; const float* ffn_b2 = (const float*)d_in[27];

  // ---- workspace layout: ~54 MB, all bf16 intermediates ----
  size_t off = 0;
  const size_t WB = (size_t)EE * EE * 2;        // 768x768 bf16 = 1.125 MB
  u16* wqT_sa = (u16*)wsoff(d_ws, off, WB);
  u16* wkT_sa = (u16*)wsoff(d_ws, off, WB);
  u16* wvT_sa = (u16*)wsoff(d_ws, off, WB);
  u16* wqT_ca = (u16*)wsoff(d_ws, off, WB);
  u16* wkT_ca = (u16*)wsoff(d_ws, off, WB);
  u16* wvT_ca = (u16*)wsoff(d_ws, off, WB);
  u16* woT_sa = (u16*)wsoff(d_ws, off, WB);
  u16* woT_ca = (u16*)wsoff(d_ws, off, WB);
  u16* w1T    = (u16*)wsoff(d_ws, off, (size_t)EE * MM * 2);   // 4.5 MB
  u16* w2T    = (u16*)wsoff(d_ws, off, (size_t)EE * MM * 2);   // 4.5 MB
  const size_t AB = (size_t)NROWS * EE * 2;     // 4096x768 bf16 = 6 MB
  u16* slot0 = (u16*)wsoff(d_ws, off, AB);      // ln out / attn out
  u16* qb    = (u16*)wsoff(d_ws, off, AB);
  u16* kb    = (u16*)wsoff(d_ws, off, AB);
  u16* vb    = (u16*)wsoff(d_ws, off, AB);
  u16* x1    = (u16*)wsoff(d_ws, off, AB);      // residual after SA
  u16* x2    = (u16*)wsoff(d_ws, off, AB);      // residual after CA
  u16* f1    = qb;  // FFN hidden [4096x3072] aliases qb,kb,vb,x1 (24 MB, dead)

  dim3 tb(32, 8);
  // weight transposes (fp32 -> bf16): per-head [H][E][D]->[H*D][E]; [R][C]->[C][R]
  transpose_k<<<dim3(2, 24, 12), tb, 0, stream>>>(sa_wq, wqT_sa, EE, DDIM);
  transpose_k<<<dim3(2, 24, 12), tb, 0, stream>>>(sa_wk, wkT_sa, EE, DDIM);
  transpose_k<<<dim3(2, 24, 12), tb, 0, stream>>>(sa_wv, wvT_sa, EE, DDIM);
  transpose_k<<<dim3(2, 24, 12), tb, 0, stream>>>(ca_wq, wqT_ca, EE, DDIM);
  transpose_k<<<dim3(2, 24, 12), tb, 0, stream>>>(ca_wk, wkT_ca, EE, DDIM);
  transpose_k<<<dim3(2, 24, 12), tb, 0, stream>>>(ca_wv, wvT_ca, EE, DDIM);
  transpose_k<<<dim3(24, 24, 1), tb, 0, stream>>>(sa_wo, woT_sa, EE, EE);
  transpose_k<<<dim3(24, 24, 1), tb, 0, stream>>>(ca_wo, woT_ca, EE, EE);
  transpose_k<<<dim3(96, 24, 1), tb, 0, stream>>>(ffn_w1, w1T, EE, MM);
  transpose_k<<<dim3(24, 96, 1), tb, 0, stream>>>(ffn_w2, w2T, MM, EE);

  dim3 g768(12, 64), g3072(48, 64);

  // --- self-attention block ---
  layernorm_k<float><<<NROWS, 256, 0, stream>>>(target, ln1_g, ln1_b, slot0);
  gemm_k<u16, 0, false, u16><<<g768, 256, 0, stream>>>(slot0, wqT_sa, sa_bq, nullptr, qb, NROWS, EE, EE);
  gemm_k<u16, 0, false, u16><<<g768, 256, 0, stream>>>(slot0, wkT_sa, sa_bk, nullptr, kb, NROWS, EE, EE);
  gemm_k<u16, 0, false, u16><<<g768, 256, 0, stream>>>(slot0, wvT_sa, sa_bv, nullptr, vb, NROWS, EE, EE);
  attn_k<true><<<dim3(16, 12, 4), 256, 0, stream>>>(qb, kb, vb, slot0);
  gemm_k<u16, 1, false, u16><<<g768, 256, 0, stream>>>(slot0, woT_sa, sa_bo, target, x1, NROWS, EE, EE);

  // --- cross-attention block ---
  layernorm_k<u16><<<NROWS, 256, 0, stream>>>(x1, ln2_g, ln2_b, slot0);
  gemm_k<u16, 0, false, u16><<<g768, 256, 0, stream>>>(slot0, wqT_ca, ca_bq, nullptr, qb, NROWS, EE, EE);
  gemm_k<float, 0, false, u16><<<g768, 256, 0, stream>>>(memory, wkT_ca, ca_bk, nullptr, kb, NROWS, EE, EE);
  gemm_k<float, 0, false, u16><<<g768, 256, 0, stream>>>(memory, wvT_ca, ca_bv, nullptr, vb, NROWS, EE, EE);
  attn_k<false><<<dim3(16, 12, 4), 256, 0, stream>>>(qb, kb, vb, slot0);
  gemm_k<u16, 2, false, u16><<<g768, 256, 0, stream>>>(slot0, woT_ca, ca_bo, x1, x2, NROWS, EE, EE);

  // --- FFN block ---
  layernorm_k<u16><<<NROWS, 256, 0, stream>>>(x2, ln3_g, ln3_b, slot0);
  gemm_k<u16, 0, true, u16><<<g3072, 256, 0, stream>>>(slot0, w1T, ffn_b1, nullptr, f1, NROWS, MM, EE);
  gemm_k<u16, 2, false, float><<<g768, 256, 0, stream>>>(f1, w2T, ffn_b2, x2, (float*)d_out, NROWS, EE, MM);
}